// Round 9
// baseline (231.535 us; speedup 1.0000x reference)
//
#include <hip/hip_runtime.h>
#include <math.h>

// B=16, H=12, S=1024, D=64.  BH=192, rows = B*H*S = 196608.
// R9: split pipeline (proj -> attn), register-slim attn for 3 waves/SIMD.
//   R8 post-mortem: unified regs = 116 arch + 64 acc = ~180/wave -> 2
//   waves/SIMD (cliff at 170) in every 256-row fused variant; in-loop K/V
//   proj is what carries the fat (lw ptrs, 20 bias regs, prefetch, +16 MFMA
//   per kb on the critical path).  Barrier count was proven a non-factor.
//   - proj kernel: R1's proj_qkv (measured ~39us) + inline fp32->bf16 for x
//     and W (drops the prep launch) + linear fragment-major lw (conflict-
//     free).  LDS 49.9KB -> 3 blocks/CU.
//   - attn kernel: R1's attn core (best measured: 78us) with no lw / no bias
//     regs / no prefetch regs -> unified ~150 < 170 -> 3 waves/SIMD
//     (launch_bounds(256,3)); K/V tile loads issued after barrier A, latency
//     covered by cross-block TLP at 3 blocks/CU; Wo converted inline in the
//     epilogue from fp32 (R4-proven).
// ws layout (bf16): Q[NE] | K[NE] | Vt_perm[NE]   (75.5 MB)
//
// KEY-PERMUTATION TRICK (unchanged): P^T exits QK in C-layout; reinterpreted
// as a B-fragment it supplies key kappa(s) at MFMA k-slot s.  Vt and Wo are
// stored/loaded pre-permuted by kappa so P and O feed MFMA from registers.
// kappa: s = 16t + 4q + r  ->  32*(t>>1) + 8*q + 4*(t&1) + r.

typedef __bf16 bf16x8 __attribute__((ext_vector_type(8)));
typedef float  f32x4  __attribute__((ext_vector_type(4)));

#define MFMA(a, b, c) __builtin_amdgcn_mfma_f32_16x16x32_bf16((a), (b), (c), 0, 0, 0)

static constexpr int S = 1024;
static constexpr int PAD = 72;      // 144 B row stride: 16B-aligned, breaks 128B aliasing
static constexpr size_t NE = 196608ull * 64ull;
// Q prescale: 1/sqrt(64) * log2(e)  -> scores arrive pre-scaled for exp2
static constexpr float QSCALE = 0.125f * 1.4426950408889634f;

__device__ inline unsigned long long pack4bf(float a, float b, float c, float d) {
    union { __bf16 h[4]; unsigned long long u; } pk;
    pk.h[0] = (__bf16)a; pk.h[1] = (__bf16)b; pk.h[2] = (__bf16)c; pk.h[3] = (__bf16)d;
    return pk.u;
}

union frag_u { bf16x8 v; unsigned long long u[2]; };

// ---------------------------------------------------------------------------
// Kernel 0: Q/K/V projection, 128 rows/block (grid 1536), all conversions
// inline.  Q (QSCALE'd) and K stored row-major; Vt stored [bh][d][key-kappa].
// LDS = lx 18.4K + lbuf 18.4K + lw 12K + lb 0.75K = 49.9KB -> 3 blocks/CU.
// ---------------------------------------------------------------------------
__global__ __launch_bounds__(256, 3) void proj(
    const float* __restrict__ x,
    const float* __restrict__ Wq, const float* __restrict__ bq,
    const float* __restrict__ Wk, const float* __restrict__ bk,
    const float* __restrict__ Wv, const float* __restrict__ bv,
    __bf16* __restrict__ gq, __bf16* __restrict__ gk, __bf16* __restrict__ gvt)
{
    __shared__ __align__(16) __bf16 lx[128][PAD];
    __shared__ __align__(16) __bf16 lbuf[128][PAD];   // roundtrip; reused as [64][136] for Vt
    // Wq/Wk/Wv in linear fragment-major layout: lw[mtx][et*2+half][lane][8].
    __shared__ __align__(16) __bf16 lw[3][8][64][8];
    __shared__ float lb[3][64];

    const int tid = threadIdx.x;
    const int row_base = blockIdx.x * 128;

    // stage x fp32 -> bf16 (inline convert; bitwise same as prep's pack4bf)
    #pragma unroll
    for (int i = tid * 4; i < 8192; i += 1024) {
        float4 v = *(const float4*)(x + (size_t)row_base * 64 + i);
        int r = i >> 6, c = i & 63;
        *(unsigned long long*)&lx[r][c] = pack4bf(v.x, v.y, v.z, v.w);
    }
    // stage W fragments (fp32 -> bf16 inline, linear fragment-major)
    #pragma unroll
    for (int c = tid; c < 1536; c += 256) {
        int mtx = c >> 9, rest = c & 511;
        int fe = rest >> 6, ln = rest & 63;
        int mm = ln & 15, qq = ln >> 4;
        int et = fe >> 1, half = fe & 1;
        const float* src = (mtx == 0 ? Wq : mtx == 1 ? Wk : Wv)
                           + (size_t)(et * 16 + mm) * 64 + half * 32 + qq * 8;
        float4 u0 = *(const float4*)(src);
        float4 u1 = *(const float4*)(src + 4);
        *(unsigned long long*)&lw[mtx][fe][ln][0] = pack4bf(u0.x, u0.y, u0.z, u0.w);
        *(unsigned long long*)&lw[mtx][fe][ln][4] = pack4bf(u1.x, u1.y, u1.z, u1.w);
    }
    if (tid < 64) { lb[0][tid] = bq[tid]; lb[1][tid] = bk[tid]; lb[2][tid] = bv[tid]; }
    __syncthreads();

    const int w = tid >> 6, lane = tid & 63, m = lane & 15, quad = lane >> 4;
    const int bh = row_base >> 10;
    const int s_base = row_base & 1023;

    bf16x8 xf[2][2];
    #pragma unroll
    for (int g = 0; g < 2; g++) {
        xf[g][0] = *(const bf16x8*)&lx[w * 32 + g * 16 + m][quad * 8];
        xf[g][1] = *(const bf16x8*)&lx[w * 32 + g * 16 + m][32 + quad * 8];
    }

    // ---- Q (QSCALE'd) and K: compute, roundtrip, coalesced store ----
    #pragma unroll
    for (int mtx = 0; mtx < 2; mtx++) {
        #pragma unroll
        for (int et = 0; et < 4; et++) {
            bf16x8 wf0 = *(const bf16x8*)&lw[mtx][et * 2 + 0][lane][0];
            bf16x8 wf1 = *(const bf16x8*)&lw[mtx][et * 2 + 1][lane][0];
            float4 bias = *(const float4*)&lb[mtx][et * 16 + quad * 4];
            #pragma unroll
            for (int g = 0; g < 2; g++) {
                f32x4 acc = {0.f, 0.f, 0.f, 0.f};
                acc = MFMA(wf0, xf[g][0], acc);
                acc = MFMA(wf1, xf[g][1], acc);
                unsigned long long u;
                if (mtx == 0)
                    u = pack4bf((acc[0] + bias.x) * QSCALE, (acc[1] + bias.y) * QSCALE,
                                (acc[2] + bias.z) * QSCALE, (acc[3] + bias.w) * QSCALE);
                else
                    u = pack4bf(acc[0] + bias.x, acc[1] + bias.y,
                                acc[2] + bias.z, acc[3] + bias.w);
                *(unsigned long long*)&lbuf[w * 32 + g * 16 + m][et * 16 + quad * 4] = u;
            }
        }
        __syncthreads();
        __bf16* dst = (mtx == 0 ? gq : gk);
        #pragma unroll
        for (int it = 0; it < 4; it++) {
            int idx = it * 256 + tid;
            int row = idx >> 3, col = (idx & 7) * 8;
            *(uint4*)(dst + ((size_t)row_base + row) * 64 + col) = *(uint4*)&lbuf[row][col];
        }
        __syncthreads();
    }

    // ---- V path: rows s_local = w*32+g*16+quad*4+r -> kappa-permuted pos ----
    __bf16 (*lvt)[136] = (__bf16(*)[136])&lbuf[0][0];
    #pragma unroll
    for (int et = 0; et < 4; et++) {
        bf16x8 wf0 = *(const bf16x8*)&lw[2][et * 2 + 0][lane][0];
        bf16x8 wf1 = *(const bf16x8*)&lw[2][et * 2 + 1][lane][0];
        const float bias = lb[2][et * 16 + m];
        #pragma unroll
        for (int g = 0; g < 2; g++) {
            f32x4 acc = {0.f, 0.f, 0.f, 0.f};
            acc = MFMA(xf[g][0], wf0, acc);
            acc = MFMA(xf[g][1], wf1, acc);
            // key group: group64 = w>>1, t' = (2w+g)&3, q' = quad
            const int tp = (2 * w + g) & 3;
            const int p0 = 64 * (w >> 1) + 32 * (tp >> 1) + 8 * quad + 4 * (tp & 1);
            *(unsigned long long*)&lvt[et * 16 + m][p0] =
                pack4bf(acc[0] + bias, acc[1] + bias, acc[2] + bias, acc[3] + bias);
        }
    }
    __syncthreads();
    #pragma unroll
    for (int it = 0; it < 4; it++) {
        int idx = it * 256 + tid;
        int row = idx >> 4, col = (idx & 15) * 8;
        *(uint4*)(gvt + ((size_t)bh * 64 + row) * 1024 + s_base + col) = *(uint4*)&lvt[row][col];
    }
}

// ---------------------------------------------------------------------------
// Kernel 1: flash attention + fused output projection (register-slim).
// Grid (192 bh, 4 qb) x 256.  LDS = lk + lv = 18.4 KB.  No lw / bias /
// prefetch regs in the loop -> unified ~<170 -> 3 waves/SIMD target.
// ---------------------------------------------------------------------------
__global__ __launch_bounds__(256, 3) void attn(
    const __bf16* __restrict__ gq, const __bf16* __restrict__ gk,
    const __bf16* __restrict__ gvt, const float* __restrict__ Wo,
    const float* __restrict__ bo, float* __restrict__ out)
{
    __shared__ __align__(16) __bf16 lk[64][PAD];        // K tile [key][d]
    __shared__ __align__(16) __bf16 lv[64][PAD];        // Vt tile [d][key-perm]

    const int tid = threadIdx.x;
    const int w = tid >> 6, lane = tid & 63, m = lane & 15, quad = lane >> 4;
    const int bh = blockIdx.x;
    const int q0 = blockIdx.y * 256 + w * 64;

    bf16x8 qf[4][2];
    #pragma unroll
    for (int g = 0; g < 4; g++) {
        const __bf16* qrow = gq + ((size_t)bh * S + q0 + g * 16 + m) * 64;
        qf[g][0] = *(const bf16x8*)(qrow + quad * 8);
        qf[g][1] = *(const bf16x8*)(qrow + 32 + quad * 8);
    }

    f32x4 o[4][4];
    float lsum[4] = {0.f, 0.f, 0.f, 0.f};
    #pragma unroll
    for (int g = 0; g < 4; g++)
        #pragma unroll
        for (int n = 0; n < 4; n++) o[g][n] = {0.f, 0.f, 0.f, 0.f};

    const int sr = tid >> 3;            // 0..31
    const int sc = (tid & 7) * 8;       // 16B chunk col
    const __bf16* kbase = gk + (size_t)bh * S * 64;
    const __bf16* vbase = gvt + (size_t)bh * 64 * 1024;

    for (int kb = 0; kb < 16; kb++) {
        __syncthreads();                // A: lk/lv free (prev compute done)
        {
            const int nb = kb * 64;
            uint4 k0 = *(const uint4*)(kbase + (size_t)(nb + sr) * 64 + sc);
            uint4 k1 = *(const uint4*)(kbase + (size_t)(nb + sr + 32) * 64 + sc);
            uint4 v0 = *(const uint4*)(vbase + (size_t)sr * 1024 + nb + sc);
            uint4 v1 = *(const uint4*)(vbase + (size_t)(sr + 32) * 1024 + nb + sc);
            *(uint4*)&lk[sr][sc]      = k0;
            *(uint4*)&lk[sr + 32][sc] = k1;
            *(uint4*)&lv[sr][sc]      = v0;
            *(uint4*)&lv[sr + 32][sc] = v1;
        }
        __syncthreads();                // B: tile ready

        __builtin_amdgcn_s_setprio(1);
        #pragma unroll
        for (int gp = 0; gp < 2; gp++) {
            // QK -> exp2 -> pack P^T straight into B-fragments (no LDS)
            frag_u pb[2][2];
            #pragma unroll
            for (int t = 0; t < 4; t++) {
                bf16x8 ka0 = *(const bf16x8*)&lk[t * 16 + m][quad * 8];
                bf16x8 ka1 = *(const bf16x8*)&lk[t * 16 + m][32 + quad * 8];
                #pragma unroll
                for (int gl = 0; gl < 2; gl++) {
                    const int g = gp * 2 + gl;
                    f32x4 acc = {0.f, 0.f, 0.f, 0.f};
                    acc = MFMA(ka0, qf[g][0], acc);
                    acc = MFMA(ka1, qf[g][1], acc);
                    float e0 = __builtin_amdgcn_exp2f(acc[0]);
                    float e1 = __builtin_amdgcn_exp2f(acc[1]);
                    float e2 = __builtin_amdgcn_exp2f(acc[2]);
                    float e3 = __builtin_amdgcn_exp2f(acc[3]);
                    lsum[g] += (e0 + e1) + (e2 + e3);
                    pb[gl][t >> 1].u[t & 1] = pack4bf(e0, e1, e2, e3);
                }
            }
            // PV: O^T[d][q] += Vt_perm (A) * P^T-regs (B)
            #pragma unroll
            for (int n = 0; n < 4; n++) {
                bf16x8 va0 = *(const bf16x8*)&lv[n * 16 + m][quad * 8];
                bf16x8 va1 = *(const bf16x8*)&lv[n * 16 + m][32 + quad * 8];
                #pragma unroll
                for (int gl = 0; gl < 2; gl++) {
                    const int g = gp * 2 + gl;
                    o[g][n] = MFMA(va0, pb[gl][0].v, o[g][n]);
                    o[g][n] = MFMA(va1, pb[gl][1].v, o[g][n]);
                }
            }
        }
        __builtin_amdgcn_s_setprio(0);
    }

    // ---- epilogue: l reduce, O^T regs -> A-fragments, fused @ Wo + bo ----
    #pragma unroll
    for (int g = 0; g < 4; g++) {
        lsum[g] += __shfl_xor(lsum[g], 16);
        lsum[g] += __shfl_xor(lsum[g], 32);
    }

    // Wo fragments built inline from fp32 with kappa folded into addresses:
    // wf[et][0] slots = Wo[e][4q..], Wo[e][16+4q..]; wf[et][1] = +32, +48.
    bf16x8 wf[4][2];
    #pragma unroll
    for (int et = 0; et < 4; et++) {
        const float* worow = Wo + (size_t)(et * 16 + m) * 64;
        float4 c0 = *(const float4*)(worow + 4 * quad);
        float4 c1 = *(const float4*)(worow + 16 + 4 * quad);
        float4 c2 = *(const float4*)(worow + 32 + 4 * quad);
        float4 c3 = *(const float4*)(worow + 48 + 4 * quad);
        frag_u f0, f1;
        f0.u[0] = pack4bf(c0.x, c0.y, c0.z, c0.w);
        f0.u[1] = pack4bf(c1.x, c1.y, c1.z, c1.w);
        f1.u[0] = pack4bf(c2.x, c2.y, c2.z, c2.w);
        f1.u[1] = pack4bf(c3.x, c3.y, c3.z, c3.w);
        wf[et][0] = f0.v;
        wf[et][1] = f1.v;
    }
    float biasr[4];
    #pragma unroll
    for (int et = 0; et < 4; et++) biasr[et] = bo[et * 16 + m];

    #pragma unroll
    for (int g = 0; g < 4; g++) {
        const float inv = 1.f / lsum[g];
        frag_u af0, af1;
        af0.u[0] = pack4bf(o[g][0][0] * inv, o[g][0][1] * inv, o[g][0][2] * inv, o[g][0][3] * inv);
        af0.u[1] = pack4bf(o[g][1][0] * inv, o[g][1][1] * inv, o[g][1][2] * inv, o[g][1][3] * inv);
        af1.u[0] = pack4bf(o[g][2][0] * inv, o[g][2][1] * inv, o[g][2][2] * inv, o[g][2][3] * inv);
        af1.u[1] = pack4bf(o[g][3][0] * inv, o[g][3][1] * inv, o[g][3][2] * inv, o[g][3][3] * inv);
        #pragma unroll
        for (int et = 0; et < 4; et++) {
            f32x4 acc = {0.f, 0.f, 0.f, 0.f};
            acc = MFMA(af0.v, wf[et][0], acc);
            acc = MFMA(af1.v, wf[et][1], acc);
            #pragma unroll
            for (int r = 0; r < 4; r++) {
                size_t row = (size_t)bh * S + q0 + g * 16 + quad * 4 + r;
                out[row * 64 + et * 16 + m] = acc[r] + biasr[et];
            }
        }
    }
}

// ---------------------------------------------------------------------------
extern "C" void kernel_launch(void* const* d_in, const int* in_sizes, int n_in,
                              void* d_out, int out_size, void* d_ws, size_t ws_size,
                              hipStream_t stream) {
    const float* x  = (const float*)d_in[0];
    const float* Wq = (const float*)d_in[1];
    const float* bq = (const float*)d_in[2];
    const float* Wk = (const float*)d_in[3];
    const float* bk = (const float*)d_in[4];
    const float* Wv = (const float*)d_in[5];
    const float* bv = (const float*)d_in[6];
    const float* Wo = (const float*)d_in[7];
    const float* bo = (const float*)d_in[8];
    float* out = (float*)d_out;

    __bf16* gq  = (__bf16*)d_ws;
    __bf16* gk  = gq + NE;
    __bf16* gvt = gk + NE;

    proj<<<1536, 256, 0, stream>>>(x, Wq, bq, Wk, bk, Wv, bv, gq, gk, gvt);
    attn<<<dim3(192, 4), 256, 0, stream>>>(gq, gk, gvt, Wo, bo, out);
}

// Round 10
// 207.256 us; speedup vs baseline: 1.1171x; 1.1171x over previous
//
#include <hip/hip_runtime.h>
#include <math.h>

// B=16, H=12, S=1024, D=64.  BH=192, rows = B*H*S = 196608.
// R10: split pipeline; occupancy via GEOMETRY, not register caps.
//   R9 post-mortem (3rd spill: R3/R6/R9): the 256-row/4-wave shape carries
//   ~180 unified regs (64 acc + ~115 arch) -> spills under any cap < 256;
//   it is locked to 2 waves/SIMD.  Fix by shrinking per-wave state:
//   - attn: 512 threads, 8 waves, 32 q-rows/wave (same 256-row block).
//     o[2][4]=32 acc + qf[2][2]=16 -> ~110 unified -> fits lb(512,4)
//     = 4 waves/SIMD honestly.  One K/V staging serves 8 waves of compute.
//   - Q never touches HBM: attn projects its own Q rows in the prologue
//     (R4/R7-proven, x+Wq fp32 read inline, bitwise-identical packs);
//     proj kernel computes only K and kappa-permuted Vt.
// ws layout (bf16): K[NE] | Vt_perm[NE]   (50.3 MB)
//
// KEY-PERMUTATION TRICK (unchanged): P^T exits QK in C-layout; reinterpreted
// as a B-fragment it supplies key kappa(s) at MFMA k-slot s.  Vt and Wo are
// stored/loaded pre-permuted by kappa so P and O feed MFMA from registers.
// kappa: s = 16t + 4q + r  ->  32*(t>>1) + 8*q + 4*(t&1) + r.

typedef __bf16 bf16x8 __attribute__((ext_vector_type(8)));
typedef float  f32x4  __attribute__((ext_vector_type(4)));

#define MFMA(a, b, c) __builtin_amdgcn_mfma_f32_16x16x32_bf16((a), (b), (c), 0, 0, 0)

static constexpr int S = 1024;
static constexpr int PAD = 72;      // 144 B row stride: 16B-aligned, breaks 128B aliasing
static constexpr size_t NE = 196608ull * 64ull;
// Q prescale: 1/sqrt(64) * log2(e)  -> scores arrive pre-scaled for exp2
static constexpr float QSCALE = 0.125f * 1.4426950408889634f;

__device__ inline unsigned long long pack4bf(float a, float b, float c, float d) {
    union { __bf16 h[4]; unsigned long long u; } pk;
    pk.h[0] = (__bf16)a; pk.h[1] = (__bf16)b; pk.h[2] = (__bf16)c; pk.h[3] = (__bf16)d;
    return pk.u;
}

union frag_u { bf16x8 v; unsigned long long u[2]; };

// ---------------------------------------------------------------------------
// Kernel 0: K/Vt projection, 128 rows/block (grid 1536), conversions inline.
// K stored row-major; Vt stored [bh][d][key-kappa].
// LDS = lx 18.4K + lbuf 18.4K + lw 8K + lb 0.5K = 45.3 KB -> 3 blocks/CU.
// ---------------------------------------------------------------------------
__global__ __launch_bounds__(256, 3) void projkv(
    const float* __restrict__ x,
    const float* __restrict__ Wk, const float* __restrict__ bk,
    const float* __restrict__ Wv, const float* __restrict__ bv,
    __bf16* __restrict__ gk, __bf16* __restrict__ gvt)
{
    __shared__ __align__(16) __bf16 lx[128][PAD];
    __shared__ __align__(16) __bf16 lbuf[128][PAD];   // roundtrip; reused as [64][136] for Vt
    // Wk/Wv in linear fragment-major layout: lw[mtx][et*2+half][lane][8].
    __shared__ __align__(16) __bf16 lw[2][8][64][8];
    __shared__ float lb[2][64];

    const int tid = threadIdx.x;
    const int row_base = blockIdx.x * 128;

    #pragma unroll
    for (int i = tid * 4; i < 8192; i += 1024) {
        float4 v = *(const float4*)(x + (size_t)row_base * 64 + i);
        int r = i >> 6, c = i & 63;
        *(unsigned long long*)&lx[r][c] = pack4bf(v.x, v.y, v.z, v.w);
    }
    #pragma unroll
    for (int c = tid; c < 1024; c += 256) {
        int mtx = c >> 9, rest = c & 511;
        int fe = rest >> 6, ln = rest & 63;
        int mm = ln & 15, qq = ln >> 4;
        int et = fe >> 1, half = fe & 1;
        const float* src = (mtx ? Wv : Wk) + (size_t)(et * 16 + mm) * 64 + half * 32 + qq * 8;
        float4 u0 = *(const float4*)(src);
        float4 u1 = *(const float4*)(src + 4);
        *(unsigned long long*)&lw[mtx][fe][ln][0] = pack4bf(u0.x, u0.y, u0.z, u0.w);
        *(unsigned long long*)&lw[mtx][fe][ln][4] = pack4bf(u1.x, u1.y, u1.z, u1.w);
    }
    if (tid < 64) { lb[0][tid] = bk[tid]; lb[1][tid] = bv[tid]; }
    __syncthreads();

    const int w = tid >> 6, lane = tid & 63, m = lane & 15, quad = lane >> 4;
    const int bh = row_base >> 10;
    const int s_base = row_base & 1023;

    bf16x8 xf[2][2];
    #pragma unroll
    for (int g = 0; g < 2; g++) {
        xf[g][0] = *(const bf16x8*)&lx[w * 32 + g * 16 + m][quad * 8];
        xf[g][1] = *(const bf16x8*)&lx[w * 32 + g * 16 + m][32 + quad * 8];
    }

    // ---- K: compute, roundtrip, coalesced store ----
    #pragma unroll
    for (int et = 0; et < 4; et++) {
        bf16x8 wf0 = *(const bf16x8*)&lw[0][et * 2 + 0][lane][0];
        bf16x8 wf1 = *(const bf16x8*)&lw[0][et * 2 + 1][lane][0];
        float4 bias = *(const float4*)&lb[0][et * 16 + quad * 4];
        #pragma unroll
        for (int g = 0; g < 2; g++) {
            f32x4 acc = {0.f, 0.f, 0.f, 0.f};
            acc = MFMA(wf0, xf[g][0], acc);
            acc = MFMA(wf1, xf[g][1], acc);
            *(unsigned long long*)&lbuf[w * 32 + g * 16 + m][et * 16 + quad * 4] =
                pack4bf(acc[0] + bias.x, acc[1] + bias.y,
                        acc[2] + bias.z, acc[3] + bias.w);
        }
    }
    __syncthreads();
    #pragma unroll
    for (int it = 0; it < 4; it++) {
        int idx = it * 256 + tid;
        int row = idx >> 3, col = (idx & 7) * 8;
        *(uint4*)(gk + ((size_t)row_base + row) * 64 + col) = *(uint4*)&lbuf[row][col];
    }
    __syncthreads();

    // ---- V path: rows s_local = w*32+g*16+quad*4+r -> kappa-permuted pos ----
    __bf16 (*lvt)[136] = (__bf16(*)[136])&lbuf[0][0];
    #pragma unroll
    for (int et = 0; et < 4; et++) {
        bf16x8 wf0 = *(const bf16x8*)&lw[1][et * 2 + 0][lane][0];
        bf16x8 wf1 = *(const bf16x8*)&lw[1][et * 2 + 1][lane][0];
        const float bias = lb[1][et * 16 + m];
        #pragma unroll
        for (int g = 0; g < 2; g++) {
            f32x4 acc = {0.f, 0.f, 0.f, 0.f};
            acc = MFMA(xf[g][0], wf0, acc);
            acc = MFMA(xf[g][1], wf1, acc);
            const int tp = (2 * w + g) & 3;
            const int p0 = 64 * (w >> 1) + 32 * (tp >> 1) + 8 * quad + 4 * (tp & 1);
            *(unsigned long long*)&lvt[et * 16 + m][p0] =
                pack4bf(acc[0] + bias, acc[1] + bias, acc[2] + bias, acc[3] + bias);
        }
    }
    __syncthreads();
    #pragma unroll
    for (int it = 0; it < 4; it++) {
        int idx = it * 256 + tid;
        int row = idx >> 4, col = (idx & 15) * 8;
        *(uint4*)(gvt + ((size_t)bh * 64 + row) * 1024 + s_base + col) = *(uint4*)&lvt[row][col];
    }
}

// ---------------------------------------------------------------------------
// Kernel 1: Q-proj prologue + flash attention + fused output projection.
// Grid (192 bh, 4 qb) x 512 threads (8 waves, 32 q-rows each).
// LDS = union(xq 36.9K | lk+lv 18.4K) = 36.9 KB.  ~110 unified regs/wave.
// ---------------------------------------------------------------------------
__global__ __launch_bounds__(512, 4) void attn(
    const float* __restrict__ x,
    const float* __restrict__ Wq, const float* __restrict__ bq,
    const __bf16* __restrict__ gk, const __bf16* __restrict__ gvt,
    const float* __restrict__ Wo, const float* __restrict__ bo,
    float* __restrict__ out)
{
    __shared__ __align__(16) union {
        __bf16 xq[256][PAD];            // prologue: x (q rows), then Q roundtrip
        struct {
            __bf16 k[64][PAD];          // K tile [key][d]
            __bf16 v[64][PAD];          // Vt tile [d][key-kappa]
        } m;
    } L;

    const int tid = threadIdx.x;
    const int w = tid >> 6, lane = tid & 63, m = lane & 15, quad = lane >> 4;
    const int bh = blockIdx.x;
    const int q0 = blockIdx.y * 256 + w * 32;

    // ---- prologue: stage my 256 x-rows fp32 -> bf16 ----
    const float* xq32 = x + ((size_t)bh * 1024 + blockIdx.y * 256) * 64;
    #pragma unroll
    for (int i = tid * 4; i < 16384; i += 2048) {
        float4 v = *(const float4*)(xq32 + i);
        int r = i >> 6, c = i & 63;
        *(unsigned long long*)&L.xq[r][c] = pack4bf(v.x, v.y, v.z, v.w);
    }
    __syncthreads();

    // Q-proj: this wave's 32 rows only (wave-private reads/writes, no barrier)
    bf16x8 xqf[2][2];
    #pragma unroll
    for (int g = 0; g < 2; g++) {
        xqf[g][0] = *(const bf16x8*)&L.xq[w * 32 + g * 16 + m][quad * 8];
        xqf[g][1] = *(const bf16x8*)&L.xq[w * 32 + g * 16 + m][32 + quad * 8];
    }
    #pragma unroll
    for (int et = 0; et < 4; et++) {
        const float* wqrow = Wq + (size_t)(et * 16 + m) * 64;
        float4 a0 = *(const float4*)(wqrow + quad * 8);
        float4 a1 = *(const float4*)(wqrow + quad * 8 + 4);
        float4 a2 = *(const float4*)(wqrow + 32 + quad * 8);
        float4 a3 = *(const float4*)(wqrow + 36 + quad * 8);
        frag_u wf0, wf1;
        wf0.u[0] = pack4bf(a0.x, a0.y, a0.z, a0.w);
        wf0.u[1] = pack4bf(a1.x, a1.y, a1.z, a1.w);
        wf1.u[0] = pack4bf(a2.x, a2.y, a2.z, a2.w);
        wf1.u[1] = pack4bf(a3.x, a3.y, a3.z, a3.w);
        float4 bias = *(const float4*)(bq + et * 16 + quad * 4);
        #pragma unroll
        for (int g = 0; g < 2; g++) {
            f32x4 acc = {0.f, 0.f, 0.f, 0.f};
            acc = MFMA(wf0.v, xqf[g][0], acc);
            acc = MFMA(wf1.v, xqf[g][1], acc);
            *(unsigned long long*)&L.xq[w * 32 + g * 16 + m][et * 16 + quad * 4] =
                pack4bf((acc[0] + bias.x) * QSCALE, (acc[1] + bias.y) * QSCALE,
                        (acc[2] + bias.z) * QSCALE, (acc[3] + bias.w) * QSCALE);
        }
    }
    bf16x8 qf[2][2];
    #pragma unroll
    for (int g = 0; g < 2; g++) {
        qf[g][0] = *(const bf16x8*)&L.xq[w * 32 + g * 16 + m][quad * 8];
        qf[g][1] = *(const bf16x8*)&L.xq[w * 32 + g * 16 + m][32 + quad * 8];
    }
    __syncthreads();    // everyone done with xq; union becomes k/v tiles

    f32x4 o[2][4];
    float lsum[2] = {0.f, 0.f};
    #pragma unroll
    for (int g = 0; g < 2; g++)
        #pragma unroll
        for (int n = 0; n < 4; n++) o[g][n] = {0.f, 0.f, 0.f, 0.f};

    const int sr = tid >> 3;            // 0..63 (512 threads)
    const int sc = (tid & 7) * 8;       // 16B chunk col
    const __bf16* kbase = gk + (size_t)bh * S * 64;
    const __bf16* vbase = gvt + (size_t)bh * 64 * 1024;

    for (int kb = 0; kb < 16; kb++) {
        __syncthreads();                // A: lk/lv free (prev compute done)
        {
            const int nb = kb * 64;
            uint4 k0 = *(const uint4*)(kbase + (size_t)(nb + sr) * 64 + sc);
            uint4 v0 = *(const uint4*)(vbase + (size_t)sr * 1024 + nb + sc);
            *(uint4*)&L.m.k[sr][sc] = k0;
            *(uint4*)&L.m.v[sr][sc] = v0;
        }
        __syncthreads();                // B: tile ready

        __builtin_amdgcn_s_setprio(1);
        // QK -> exp2 -> pack P^T straight into B-fragments (no LDS)
        frag_u pb[2][2];
        #pragma unroll
        for (int t = 0; t < 4; t++) {
            bf16x8 ka0 = *(const bf16x8*)&L.m.k[t * 16 + m][quad * 8];
            bf16x8 ka1 = *(const bf16x8*)&L.m.k[t * 16 + m][32 + quad * 8];
            #pragma unroll
            for (int g = 0; g < 2; g++) {
                f32x4 acc = {0.f, 0.f, 0.f, 0.f};
                acc = MFMA(ka0, qf[g][0], acc);
                acc = MFMA(ka1, qf[g][1], acc);
                float e0 = __builtin_amdgcn_exp2f(acc[0]);
                float e1 = __builtin_amdgcn_exp2f(acc[1]);
                float e2 = __builtin_amdgcn_exp2f(acc[2]);
                float e3 = __builtin_amdgcn_exp2f(acc[3]);
                lsum[g] += (e0 + e1) + (e2 + e3);
                pb[g][t >> 1].u[t & 1] = pack4bf(e0, e1, e2, e3);
            }
        }
        // PV: O^T[d][q] += Vt_perm (A) * P^T-regs (B)
        #pragma unroll
        for (int n = 0; n < 4; n++) {
            bf16x8 va0 = *(const bf16x8*)&L.m.v[n * 16 + m][quad * 8];
            bf16x8 va1 = *(const bf16x8*)&L.m.v[n * 16 + m][32 + quad * 8];
            #pragma unroll
            for (int g = 0; g < 2; g++) {
                o[g][n] = MFMA(va0, pb[g][0].v, o[g][n]);
                o[g][n] = MFMA(va1, pb[g][1].v, o[g][n]);
            }
        }
        __builtin_amdgcn_s_setprio(0);
    }

    // ---- epilogue: l reduce, O^T regs -> A-fragments, fused @ Wo + bo ----
    #pragma unroll
    for (int g = 0; g < 2; g++) {
        lsum[g] += __shfl_xor(lsum[g], 16);
        lsum[g] += __shfl_xor(lsum[g], 32);
    }

    // Wo fragments built inline from fp32 with kappa folded into addresses:
    bf16x8 wf[4][2];
    #pragma unroll
    for (int et = 0; et < 4; et++) {
        const float* worow = Wo + (size_t)(et * 16 + m) * 64;
        float4 c0 = *(const float4*)(worow + 4 * quad);
        float4 c1 = *(const float4*)(worow + 16 + 4 * quad);
        float4 c2 = *(const float4*)(worow + 32 + 4 * quad);
        float4 c3 = *(const float4*)(worow + 48 + 4 * quad);
        frag_u f0, f1;
        f0.u[0] = pack4bf(c0.x, c0.y, c0.z, c0.w);
        f0.u[1] = pack4bf(c1.x, c1.y, c1.z, c1.w);
        f1.u[0] = pack4bf(c2.x, c2.y, c2.z, c2.w);
        f1.u[1] = pack4bf(c3.x, c3.y, c3.z, c3.w);
        wf[et][0] = f0.v;
        wf[et][1] = f1.v;
    }
    float biasr[4];
    #pragma unroll
    for (int et = 0; et < 4; et++) biasr[et] = bo[et * 16 + m];

    #pragma unroll
    for (int g = 0; g < 2; g++) {
        const float inv = 1.f / lsum[g];
        frag_u af0, af1;
        af0.u[0] = pack4bf(o[g][0][0] * inv, o[g][0][1] * inv, o[g][0][2] * inv, o[g][0][3] * inv);
        af0.u[1] = pack4bf(o[g][1][0] * inv, o[g][1][1] * inv, o[g][1][2] * inv, o[g][1][3] * inv);
        af1.u[0] = pack4bf(o[g][2][0] * inv, o[g][2][1] * inv, o[g][2][2] * inv, o[g][2][3] * inv);
        af1.u[1] = pack4bf(o[g][3][0] * inv, o[g][3][1] * inv, o[g][3][2] * inv, o[g][3][3] * inv);
        #pragma unroll
        for (int et = 0; et < 4; et++) {
            f32x4 acc = {0.f, 0.f, 0.f, 0.f};
            acc = MFMA(af0.v, wf[et][0], acc);
            acc = MFMA(af1.v, wf[et][1], acc);
            #pragma unroll
            for (int r = 0; r < 4; r++) {
                size_t row = (size_t)bh * S + q0 + g * 16 + quad * 4 + r;
                out[row * 64 + et * 16 + m] = acc[r] + biasr[et];
            }
        }
    }
}

// ---------------------------------------------------------------------------
extern "C" void kernel_launch(void* const* d_in, const int* in_sizes, int n_in,
                              void* d_out, int out_size, void* d_ws, size_t ws_size,
                              hipStream_t stream) {
    const float* x  = (const float*)d_in[0];
    const float* Wq = (const float*)d_in[1];
    const float* bq = (const float*)d_in[2];
    const float* Wk = (const float*)d_in[3];
    const float* bk = (const float*)d_in[4];
    const float* Wv = (const float*)d_in[5];
    const float* bv = (const float*)d_in[6];
    const float* Wo = (const float*)d_in[7];
    const float* bo = (const float*)d_in[8];
    float* out = (float*)d_out;

    __bf16* gk  = (__bf16*)d_ws;
    __bf16* gvt = gk + NE;

    projkv<<<1536, 256, 0, stream>>>(x, Wk, bk, Wv, bv, gk, gvt);
    attn<<<dim3(192, 4), 512, 0, stream>>>(x, Wq, bq, gk, gvt, Wo, bo, out);
}

// Round 11
// 197.730 us; speedup vs baseline: 1.1710x; 1.0482x over previous
//
#include <hip/hip_runtime.h>
#include <math.h>

// B=16, H=12, S=1024, D=64.  BH=192, rows = B*H*S = 196608.
// R11: R10 + restored cross-iteration K/V register prefetch (the R0/R1
//   pattern that measured 78us).  R10 post-mortem: geometry fix landed
//   (VGPR 60, no spill, occ 35%, 100us) but the prefetch had been deleted --
//   loads issued after barrier A and used immediately = ~600cyc naked global
//   latency per kb x16.  R1 attn with prefetch at HALF the occupancy ran 78us.
//   Change: tile kb+1 loaded into 2 uint4 regs right after tile kb's LDS
//   writes (tile 0 hoisted before the prologue barrier); +8 VGPR, no cliff.
// ws layout (bf16): K[NE] | Vt_perm[NE]   (50.3 MB)
//
// KEY-PERMUTATION TRICK (unchanged): P^T exits QK in C-layout; reinterpreted
// as a B-fragment it supplies key kappa(s) at MFMA k-slot s.  Vt and Wo are
// stored/loaded pre-permuted by kappa so P and O feed MFMA from registers.
// kappa: s = 16t + 4q + r  ->  32*(t>>1) + 8*q + 4*(t&1) + r.

typedef __bf16 bf16x8 __attribute__((ext_vector_type(8)));
typedef float  f32x4  __attribute__((ext_vector_type(4)));

#define MFMA(a, b, c) __builtin_amdgcn_mfma_f32_16x16x32_bf16((a), (b), (c), 0, 0, 0)

static constexpr int S = 1024;
static constexpr int PAD = 72;      // 144 B row stride: 16B-aligned, breaks 128B aliasing
static constexpr size_t NE = 196608ull * 64ull;
// Q prescale: 1/sqrt(64) * log2(e)  -> scores arrive pre-scaled for exp2
static constexpr float QSCALE = 0.125f * 1.4426950408889634f;

__device__ inline unsigned long long pack4bf(float a, float b, float c, float d) {
    union { __bf16 h[4]; unsigned long long u; } pk;
    pk.h[0] = (__bf16)a; pk.h[1] = (__bf16)b; pk.h[2] = (__bf16)c; pk.h[3] = (__bf16)d;
    return pk.u;
}

union frag_u { bf16x8 v; unsigned long long u[2]; };

// ---------------------------------------------------------------------------
// Kernel 0: K/Vt projection, 128 rows/block (grid 1536), conversions inline.
// K stored row-major; Vt stored [bh][d][key-kappa].
// LDS = lx 18.4K + lbuf 18.4K + lw 8K + lb 0.5K = 45.3 KB -> 3 blocks/CU.
// ---------------------------------------------------------------------------
__global__ __launch_bounds__(256, 3) void projkv(
    const float* __restrict__ x,
    const float* __restrict__ Wk, const float* __restrict__ bk,
    const float* __restrict__ Wv, const float* __restrict__ bv,
    __bf16* __restrict__ gk, __bf16* __restrict__ gvt)
{
    __shared__ __align__(16) __bf16 lx[128][PAD];
    __shared__ __align__(16) __bf16 lbuf[128][PAD];   // roundtrip; reused as [64][136] for Vt
    // Wk/Wv in linear fragment-major layout: lw[mtx][et*2+half][lane][8].
    __shared__ __align__(16) __bf16 lw[2][8][64][8];
    __shared__ float lb[2][64];

    const int tid = threadIdx.x;
    const int row_base = blockIdx.x * 128;

    #pragma unroll
    for (int i = tid * 4; i < 8192; i += 1024) {
        float4 v = *(const float4*)(x + (size_t)row_base * 64 + i);
        int r = i >> 6, c = i & 63;
        *(unsigned long long*)&lx[r][c] = pack4bf(v.x, v.y, v.z, v.w);
    }
    #pragma unroll
    for (int c = tid; c < 1024; c += 256) {
        int mtx = c >> 9, rest = c & 511;
        int fe = rest >> 6, ln = rest & 63;
        int mm = ln & 15, qq = ln >> 4;
        int et = fe >> 1, half = fe & 1;
        const float* src = (mtx ? Wv : Wk) + (size_t)(et * 16 + mm) * 64 + half * 32 + qq * 8;
        float4 u0 = *(const float4*)(src);
        float4 u1 = *(const float4*)(src + 4);
        *(unsigned long long*)&lw[mtx][fe][ln][0] = pack4bf(u0.x, u0.y, u0.z, u0.w);
        *(unsigned long long*)&lw[mtx][fe][ln][4] = pack4bf(u1.x, u1.y, u1.z, u1.w);
    }
    if (tid < 64) { lb[0][tid] = bk[tid]; lb[1][tid] = bv[tid]; }
    __syncthreads();

    const int w = tid >> 6, lane = tid & 63, m = lane & 15, quad = lane >> 4;
    const int bh = row_base >> 10;
    const int s_base = row_base & 1023;

    bf16x8 xf[2][2];
    #pragma unroll
    for (int g = 0; g < 2; g++) {
        xf[g][0] = *(const bf16x8*)&lx[w * 32 + g * 16 + m][quad * 8];
        xf[g][1] = *(const bf16x8*)&lx[w * 32 + g * 16 + m][32 + quad * 8];
    }

    // ---- K: compute, roundtrip, coalesced store ----
    #pragma unroll
    for (int et = 0; et < 4; et++) {
        bf16x8 wf0 = *(const bf16x8*)&lw[0][et * 2 + 0][lane][0];
        bf16x8 wf1 = *(const bf16x8*)&lw[0][et * 2 + 1][lane][0];
        float4 bias = *(const float4*)&lb[0][et * 16 + quad * 4];
        #pragma unroll
        for (int g = 0; g < 2; g++) {
            f32x4 acc = {0.f, 0.f, 0.f, 0.f};
            acc = MFMA(wf0, xf[g][0], acc);
            acc = MFMA(wf1, xf[g][1], acc);
            *(unsigned long long*)&lbuf[w * 32 + g * 16 + m][et * 16 + quad * 4] =
                pack4bf(acc[0] + bias.x, acc[1] + bias.y,
                        acc[2] + bias.z, acc[3] + bias.w);
        }
    }
    __syncthreads();
    #pragma unroll
    for (int it = 0; it < 4; it++) {
        int idx = it * 256 + tid;
        int row = idx >> 3, col = (idx & 7) * 8;
        *(uint4*)(gk + ((size_t)row_base + row) * 64 + col) = *(uint4*)&lbuf[row][col];
    }
    __syncthreads();

    // ---- V path: rows s_local = w*32+g*16+quad*4+r -> kappa-permuted pos ----
    __bf16 (*lvt)[136] = (__bf16(*)[136])&lbuf[0][0];
    #pragma unroll
    for (int et = 0; et < 4; et++) {
        bf16x8 wf0 = *(const bf16x8*)&lw[1][et * 2 + 0][lane][0];
        bf16x8 wf1 = *(const bf16x8*)&lw[1][et * 2 + 1][lane][0];
        const float bias = lb[1][et * 16 + m];
        #pragma unroll
        for (int g = 0; g < 2; g++) {
            f32x4 acc = {0.f, 0.f, 0.f, 0.f};
            acc = MFMA(xf[g][0], wf0, acc);
            acc = MFMA(xf[g][1], wf1, acc);
            const int tp = (2 * w + g) & 3;
            const int p0 = 64 * (w >> 1) + 32 * (tp >> 1) + 8 * quad + 4 * (tp & 1);
            *(unsigned long long*)&lvt[et * 16 + m][p0] =
                pack4bf(acc[0] + bias, acc[1] + bias, acc[2] + bias, acc[3] + bias);
        }
    }
    __syncthreads();
    #pragma unroll
    for (int it = 0; it < 4; it++) {
        int idx = it * 256 + tid;
        int row = idx >> 4, col = (idx & 15) * 8;
        *(uint4*)(gvt + ((size_t)bh * 64 + row) * 1024 + s_base + col) = *(uint4*)&lvt[row][col];
    }
}

// ---------------------------------------------------------------------------
// Kernel 1: Q-proj prologue + flash attention + fused output projection.
// Grid (192 bh, 4 qb) x 512 threads (8 waves, 32 q-rows each).
// LDS = union(xq 36.9K | lk+lv 18.4K) = 36.9 KB.  K/V tiles prefetched into
// registers one iteration ahead (R0/R1-proven).
// ---------------------------------------------------------------------------
__global__ __launch_bounds__(512, 4) void attn(
    const float* __restrict__ x,
    const float* __restrict__ Wq, const float* __restrict__ bq,
    const __bf16* __restrict__ gk, const __bf16* __restrict__ gvt,
    const float* __restrict__ Wo, const float* __restrict__ bo,
    float* __restrict__ out)
{
    __shared__ __align__(16) union {
        __bf16 xq[256][PAD];            // prologue: x (q rows), then Q roundtrip
        struct {
            __bf16 k[64][PAD];          // K tile [key][d]
            __bf16 v[64][PAD];          // Vt tile [d][key-kappa]
        } m;
    } L;

    const int tid = threadIdx.x;
    const int w = tid >> 6, lane = tid & 63, m = lane & 15, quad = lane >> 4;
    const int bh = blockIdx.x;
    const int q0 = blockIdx.y * 256 + w * 32;

    // ---- prologue: stage my 256 x-rows fp32 -> bf16 ----
    const float* xq32 = x + ((size_t)bh * 1024 + blockIdx.y * 256) * 64;
    #pragma unroll
    for (int i = tid * 4; i < 16384; i += 2048) {
        float4 v = *(const float4*)(xq32 + i);
        int r = i >> 6, c = i & 63;
        *(unsigned long long*)&L.xq[r][c] = pack4bf(v.x, v.y, v.z, v.w);
    }
    __syncthreads();

    // Q-proj: this wave's 32 rows only (wave-private reads/writes, no barrier)
    bf16x8 xqf[2][2];
    #pragma unroll
    for (int g = 0; g < 2; g++) {
        xqf[g][0] = *(const bf16x8*)&L.xq[w * 32 + g * 16 + m][quad * 8];
        xqf[g][1] = *(const bf16x8*)&L.xq[w * 32 + g * 16 + m][32 + quad * 8];
    }
    #pragma unroll
    for (int et = 0; et < 4; et++) {
        const float* wqrow = Wq + (size_t)(et * 16 + m) * 64;
        float4 a0 = *(const float4*)(wqrow + quad * 8);
        float4 a1 = *(const float4*)(wqrow + quad * 8 + 4);
        float4 a2 = *(const float4*)(wqrow + 32 + quad * 8);
        float4 a3 = *(const float4*)(wqrow + 36 + quad * 8);
        frag_u wf0, wf1;
        wf0.u[0] = pack4bf(a0.x, a0.y, a0.z, a0.w);
        wf0.u[1] = pack4bf(a1.x, a1.y, a1.z, a1.w);
        wf1.u[0] = pack4bf(a2.x, a2.y, a2.z, a2.w);
        wf1.u[1] = pack4bf(a3.x, a3.y, a3.z, a3.w);
        float4 bias = *(const float4*)(bq + et * 16 + quad * 4);
        #pragma unroll
        for (int g = 0; g < 2; g++) {
            f32x4 acc = {0.f, 0.f, 0.f, 0.f};
            acc = MFMA(wf0.v, xqf[g][0], acc);
            acc = MFMA(wf1.v, xqf[g][1], acc);
            *(unsigned long long*)&L.xq[w * 32 + g * 16 + m][et * 16 + quad * 4] =
                pack4bf((acc[0] + bias.x) * QSCALE, (acc[1] + bias.y) * QSCALE,
                        (acc[2] + bias.z) * QSCALE, (acc[3] + bias.w) * QSCALE);
        }
    }
    bf16x8 qf[2][2];
    #pragma unroll
    for (int g = 0; g < 2; g++) {
        qf[g][0] = *(const bf16x8*)&L.xq[w * 32 + g * 16 + m][quad * 8];
        qf[g][1] = *(const bf16x8*)&L.xq[w * 32 + g * 16 + m][32 + quad * 8];
    }

    const int sr = tid >> 3;            // 0..63 (512 threads)
    const int sc = (tid & 7) * 8;       // 16B chunk col
    const __bf16* kbase = gk + (size_t)bh * S * 64;
    const __bf16* vbase = gvt + (size_t)bh * 64 * 1024;

    // prefetch tile 0 into regs (global loads; legal before the barrier)
    uint4 kreg = *(const uint4*)(kbase + (size_t)sr * 64 + sc);
    uint4 vreg = *(const uint4*)(vbase + (size_t)sr * 1024 + sc);

    __syncthreads();    // everyone done with xq; union becomes k/v tiles

    f32x4 o[2][4];
    float lsum[2] = {0.f, 0.f};
    #pragma unroll
    for (int g = 0; g < 2; g++)
        #pragma unroll
        for (int n = 0; n < 4; n++) o[g][n] = {0.f, 0.f, 0.f, 0.f};

    for (int kb = 0; kb < 16; kb++) {
        __syncthreads();                // A: lk/lv free (prev compute done)
        *(uint4*)&L.m.k[sr][sc] = kreg;
        *(uint4*)&L.m.v[sr][sc] = vreg;
        if (kb < 15) {                  // issue next tile's loads NOW
            const int nb = (kb + 1) * 64;
            kreg = *(const uint4*)(kbase + (size_t)(nb + sr) * 64 + sc);
            vreg = *(const uint4*)(vbase + (size_t)sr * 1024 + nb + sc);
        }
        __syncthreads();                // B: tile ready

        __builtin_amdgcn_s_setprio(1);
        // QK -> exp2 -> pack P^T straight into B-fragments (no LDS)
        frag_u pb[2][2];
        #pragma unroll
        for (int t = 0; t < 4; t++) {
            bf16x8 ka0 = *(const bf16x8*)&L.m.k[t * 16 + m][quad * 8];
            bf16x8 ka1 = *(const bf16x8*)&L.m.k[t * 16 + m][32 + quad * 8];
            #pragma unroll
            for (int g = 0; g < 2; g++) {
                f32x4 acc = {0.f, 0.f, 0.f, 0.f};
                acc = MFMA(ka0, qf[g][0], acc);
                acc = MFMA(ka1, qf[g][1], acc);
                float e0 = __builtin_amdgcn_exp2f(acc[0]);
                float e1 = __builtin_amdgcn_exp2f(acc[1]);
                float e2 = __builtin_amdgcn_exp2f(acc[2]);
                float e3 = __builtin_amdgcn_exp2f(acc[3]);
                lsum[g] += (e0 + e1) + (e2 + e3);
                pb[g][t >> 1].u[t & 1] = pack4bf(e0, e1, e2, e3);
            }
        }
        // PV: O^T[d][q] += Vt_perm (A) * P^T-regs (B)
        #pragma unroll
        for (int n = 0; n < 4; n++) {
            bf16x8 va0 = *(const bf16x8*)&L.m.v[n * 16 + m][quad * 8];
            bf16x8 va1 = *(const bf16x8*)&L.m.v[n * 16 + m][32 + quad * 8];
            #pragma unroll
            for (int g = 0; g < 2; g++) {
                o[g][n] = MFMA(va0, pb[g][0].v, o[g][n]);
                o[g][n] = MFMA(va1, pb[g][1].v, o[g][n]);
            }
        }
        __builtin_amdgcn_s_setprio(0);
    }

    // ---- epilogue: l reduce, O^T regs -> A-fragments, fused @ Wo + bo ----
    #pragma unroll
    for (int g = 0; g < 2; g++) {
        lsum[g] += __shfl_xor(lsum[g], 16);
        lsum[g] += __shfl_xor(lsum[g], 32);
    }

    // Wo fragments built inline from fp32 with kappa folded into addresses:
    bf16x8 wf[4][2];
    #pragma unroll
    for (int et = 0; et < 4; et++) {
        const float* worow = Wo + (size_t)(et * 16 + m) * 64;
        float4 c0 = *(const float4*)(worow + 4 * quad);
        float4 c1 = *(const float4*)(worow + 16 + 4 * quad);
        float4 c2 = *(const float4*)(worow + 32 + 4 * quad);
        float4 c3 = *(const float4*)(worow + 48 + 4 * quad);
        frag_u f0, f1;
        f0.u[0] = pack4bf(c0.x, c0.y, c0.z, c0.w);
        f0.u[1] = pack4bf(c1.x, c1.y, c1.z, c1.w);
        f1.u[0] = pack4bf(c2.x, c2.y, c2.z, c2.w);
        f1.u[1] = pack4bf(c3.x, c3.y, c3.z, c3.w);
        wf[et][0] = f0.v;
        wf[et][1] = f1.v;
    }
    float biasr[4];
    #pragma unroll
    for (int et = 0; et < 4; et++) biasr[et] = bo[et * 16 + m];

    #pragma unroll
    for (int g = 0; g < 2; g++) {
        const float inv = 1.f / lsum[g];
        frag_u af0, af1;
        af0.u[0] = pack4bf(o[g][0][0] * inv, o[g][0][1] * inv, o[g][0][2] * inv, o[g][0][3] * inv);
        af0.u[1] = pack4bf(o[g][1][0] * inv, o[g][1][1] * inv, o[g][1][2] * inv, o[g][1][3] * inv);
        af1.u[0] = pack4bf(o[g][2][0] * inv, o[g][2][1] * inv, o[g][2][2] * inv, o[g][2][3] * inv);
        af1.u[1] = pack4bf(o[g][3][0] * inv, o[g][3][1] * inv, o[g][3][2] * inv, o[g][3][3] * inv);
        #pragma unroll
        for (int et = 0; et < 4; et++) {
            f32x4 acc = {0.f, 0.f, 0.f, 0.f};
            acc = MFMA(af0.v, wf[et][0], acc);
            acc = MFMA(af1.v, wf[et][1], acc);
            #pragma unroll
            for (int r = 0; r < 4; r++) {
                size_t row = (size_t)bh * S + q0 + g * 16 + quad * 4 + r;
                out[row * 64 + et * 16 + m] = acc[r] + biasr[et];
            }
        }
    }
}

// ---------------------------------------------------------------------------
extern "C" void kernel_launch(void* const* d_in, const int* in_sizes, int n_in,
                              void* d_out, int out_size, void* d_ws, size_t ws_size,
                              hipStream_t stream) {
    const float* x  = (const float*)d_in[0];
    const float* Wq = (const float*)d_in[1];
    const float* bq = (const float*)d_in[2];
    const float* Wk = (const float*)d_in[3];
    const float* bk = (const float*)d_in[4];
    const float* Wv = (const float*)d_in[5];
    const float* bv = (const float*)d_in[6];
    const float* Wo = (const float*)d_in[7];
    const float* bo = (const float*)d_in[8];
    float* out = (float*)d_out;

    __bf16* gk  = (__bf16*)d_ws;
    __bf16* gvt = gk + NE;

    projkv<<<1536, 256, 0, stream>>>(x, Wk, bk, Wv, bv, gk, gvt);
    attn<<<dim3(192, 4), 512, 0, stream>>>(x, Wq, bq, gk, gvt, Wo, bo, out);
}